// Round 13
// baseline (91.380 us; speedup 1.0000x reference)
//
#include <hip/hip_runtime.h>

// LateralInhibitionAttention, MI355X.
// Conv3x3 of the rank-structured score matrix factorizes:
//   sum_{3x3} s[n+i][m+j] = (q[n-1]+q[n]+q[n+1]) . (k[m-1]+k[m]+k[m+1])
// so inhibited scores = [cq*q ; cs*qsum] . [k ; ksum]  (augmented 128-dim dot).
// R12 analysis: attn is LDS-BW-bound (every wave reads full K/KK/VT tile:
// 12 waves x 26KB x 16 tiles x 3 blk/CU ~ 4.6MB/CU ~ 22us floor).
// R13: 32 q-rows per wave (2 q-groups share each A-fragment read) -> LDS bytes
// per q-row halve. 2-wave 128-thread blocks, 64 q/block, grid stays 768 (=3/CU).

using short8 = __attribute__((ext_vector_type(8))) short;
using short4v = __attribute__((ext_vector_type(4))) short;
using f32x4 = __attribute__((ext_vector_type(4))) float;

#define MFMA16(a, b, c) __builtin_amdgcn_mfma_f32_16x16x32_bf16((a), (b), (c), 0, 0, 0)

__device__ __forceinline__ float b2f(short s) {
    union { unsigned u; float f; } x;
    x.u = ((unsigned)(unsigned short)s) << 16;
    return x.f;
}
__device__ __forceinline__ short f2b(float f) {  // RNE f32->bf16
    unsigned u = __float_as_uint(f);
    unsigned r = (u + 0x7FFFu + ((u >> 16) & 1u)) >> 16;
    return (short)r;
}
__device__ __forceinline__ unsigned pk2(float lo, float hi) {  // packed bf16x2, 1 VALU op
    unsigned r;
    asm("v_cvt_pk_bf16_f32 %0, %1, %2" : "=v"(r) : "v"(lo), "v"(hi));
    return r;
}
// async global->LDS, 16B per lane; lds dest must be wave-uniform base (+lane*16 implicit)
__device__ __forceinline__ void gload_lds16(const short* g, short* l) {
    __builtin_amdgcn_global_load_lds(
        (const __attribute__((address_space(1))) void*)g,
        (__attribute__((address_space(3))) void*)l, 16, 0, 0);
}

// ---------------- fused LayerNorm->bf16 (blocks 0..4095) + W->bf16 (4096..5823) ----------------
__global__ __launch_bounds__(256) void prep_kernel(const float* __restrict__ x,
                                                   const float* __restrict__ g,
                                                   const float* __restrict__ bb,
                                                   const float* __restrict__ W,
                                                   short* __restrict__ xnb,
                                                   short* __restrict__ Wb) {
    int bid = blockIdx.x, t = threadIdx.x;
    if (bid >= 4096) {  // W f32 -> bf16 chunk
        int i = ((bid - 4096) * 256 + t) * 4;
        float4 v = *(const float4*)(W + i);
        short4v o;
        o[0] = f2b(v.x); o[1] = f2b(v.y); o[2] = f2b(v.z); o[3] = f2b(v.w);
        *(short4v*)(Wb + i) = o;
        return;
    }
    int row = bid;
    const float* xr = x + (size_t)row * 768;
    float v0 = xr[t], v1 = xr[t + 256], v2 = xr[t + 512];
    float s = v0 + v1 + v2;
    float ss = v0 * v0 + v1 * v1 + v2 * v2;
#pragma unroll
    for (int o = 1; o < 64; o <<= 1) { s += __shfl_xor(s, o); ss += __shfl_xor(ss, o); }
    __shared__ float red[8];
    int w = t >> 6;
    if ((t & 63) == 0) { red[w] = s; red[4 + w] = ss; }
    __syncthreads();
    s = red[0] + red[1] + red[2] + red[3];
    ss = red[4] + red[5] + red[6] + red[7];
    float mu = s * (1.0f / 768.0f);
    float var = ss * (1.0f / 768.0f) - mu * mu;
    float rs = rsqrtf(var + 1e-5f);
    short* o = xnb + (size_t)row * 768;
    o[t]       = f2b((v0 - mu) * rs * g[t]       + bb[t]);
    o[t + 256] = f2b((v1 - mu) * rs * g[t + 256] + bb[t + 256]);
    o[t + 512] = f2b((v2 - mu) * rs * g[t + 512] + bb[t + 512]);
}

// ---------------- QKV GEMM: [4096,768]x[768,2304]^T, m97-structure (R8-proven) ----------------
__global__ __launch_bounds__(256) void qkv_gemm(const short* __restrict__ A,
                                                const short* __restrict__ B,
                                                const float* __restrict__ bias,
                                                short* __restrict__ Qb,
                                                short* __restrict__ Kb,
                                                short* __restrict__ VT) {
    __shared__ char smem[17408];
    short* As = (short*)smem;            // [128][32] bf16
    short* Bs = (short*)(smem + 8192);   // [128][32] bf16
    int t = threadIdx.x, w = t >> 6, l = t & 63, lr = l & 15, lg = l >> 4;
    int wr = w >> 1, wc = w & 1;
    int row0 = blockIdx.x * 128;
    int col0 = blockIdx.y * 128;
    const short* agp0 = A + (size_t)(row0 + (t >> 2)) * 768 + (t & 3) * 8;
    const short* agp1 = agp0 + (size_t)64 * 768;
    const short* bgp0 = B + (size_t)(col0 + (t >> 2)) * 768 + (t & 3) * 8;
    const short* bgp1 = bgp0 + (size_t)64 * 768;
    short* asl0 = As + (w * 64) * 8;
    short* asl1 = As + (256 + w * 64) * 8;
    short* bsl0 = Bs + (w * 64) * 8;
    short* bsl1 = Bs + (256 + w * 64) * 8;

    f32x4 acc[4][4];
#pragma unroll
    for (int m = 0; m < 4; ++m)
#pragma unroll
        for (int n = 0; n < 4; ++n) acc[m][n] = (f32x4){0.f, 0.f, 0.f, 0.f};

    for (int k0 = 0; k0 < 768; k0 += 32) {
        gload_lds16(agp0 + k0, asl0);
        gload_lds16(agp1 + k0, asl1);
        gload_lds16(bgp0 + k0, bsl0);
        gload_lds16(bgp1 + k0, bsl1);
        __syncthreads();
        short8 af[4], bf[4];
#pragma unroll
        for (int m = 0; m < 4; ++m)
            af[m] = *(short8*)&As[(wr * 64 + m * 16 + lr) * 32 + lg * 8];
#pragma unroll
        for (int n = 0; n < 4; ++n)
            bf[n] = *(short8*)&Bs[(wc * 64 + n * 16 + lr) * 32 + lg * 8];
#pragma unroll
        for (int m = 0; m < 4; ++m)
#pragma unroll
            for (int n = 0; n < 4; ++n)
                acc[m][n] = MFMA16(af[m], bf[n], acc[m][n]);
        __syncthreads();
    }

    int sec = blockIdx.y / 6;  // uniform per block
    if (sec < 2) {
        short* dst = sec ? Kb : Qb;
        // Q pre-scale: 1.2 * D^-0.5 * log2(e)  -> scores arrive in log2 space.
        const float scl = sec ? 1.0f : (1.2f * 0.125f * 1.44269504088896f);
#pragma unroll
        for (int n = 0; n < 4; ++n) {
            int j = col0 + wc * 64 + n * 16 + lr;
            float bs = bias[j];
            int jj = j - sec * 768;
            int h = jj >> 6, d = jj & 63;
#pragma unroll
            for (int m = 0; m < 4; ++m)
#pragma unroll
                for (int i = 0; i < 4; ++i) {
                    int row = row0 + wr * 64 + m * 16 + lg * 4 + i;
                    int b = row >> 10, n_ = row & 1023;
                    dst[(size_t)(((b * 12 + h) << 10) | n_) * 64 + d] =
                        f2b(scl * (acc[m][n][i] + bs));
                }
        }
    } else {
        // V: transpose 128x128 tile -> VT[d][n], two 64-col passes through LDS
        short* tr = (short*)smem;  // [64][136]
        int b = row0 >> 10, nin = row0 & 1023;
        int jj0 = col0 - 1536;
        for (int p = 0; p < 2; ++p) {
            __syncthreads();
            if (wc == p) {
#pragma unroll
                for (int n = 0; n < 4; ++n) {
                    int jl = n * 16 + lr;
                    float bs = bias[col0 + p * 64 + jl];
#pragma unroll
                    for (int m = 0; m < 4; ++m) {
                        int nl = wr * 64 + m * 16 + lg * 4;
                        short4v o;
#pragma unroll
                        for (int i = 0; i < 4; ++i) o[i] = f2b(acc[m][n][i] + bs);
                        *(short4v*)&tr[jl * 136 + nl] = o;
                    }
                }
            }
            __syncthreads();
            int jl = t >> 2, qd = t & 3;
            int j = jj0 + p * 64 + jl;
            int h = j >> 6, d = j & 63;
            short* vtb = VT + (size_t)(b * 12 + h) * 65536 + d * 1024 + nin + qd * 32;
#pragma unroll
            for (int u = 0; u < 4; ++u)
                *(short8*)(vtb + u * 8) = *(short8*)&tr[jl * 136 + qd * 32 + u * 8];
        }
    }
}

// ---------------- KK = k[n-1]+k[n]+k[n+1] (zero-padded) ----------------
__global__ __launch_bounds__(256) void kk_kernel(const short* __restrict__ Kb,
                                                 short* __restrict__ KK) {
    int bh = blockIdx.y;
    int t = threadIdx.x;
    int n = blockIdx.x * 32 + (t >> 3), dc = (t & 7) * 8;
    const short* kp = Kb + (size_t)bh * 65536;
    float s[8];
    short8 c = *(const short8*)(kp + n * 64 + dc);
#pragma unroll
    for (int e = 0; e < 8; ++e) s[e] = b2f(c[e]);
    if (n > 0) {
        short8 m = *(const short8*)(kp + (n - 1) * 64 + dc);
#pragma unroll
        for (int e = 0; e < 8; ++e) s[e] += b2f(m[e]);
    }
    if (n < 1023) {
        short8 p = *(const short8*)(kp + (n + 1) * 64 + dc);
#pragma unroll
        for (int e = 0; e < 8; ++e) s[e] += b2f(p[e]);
    }
    short8 o;
#pragma unroll
    for (int e = 0; e < 8; ++e) o[e] = f2b(s[e]);
    *(short8*)(KK + (size_t)bh * 65536 + n * 64 + dc) = o;
}

// ---------------- flash attention: online softmax (log2-space), 32 q-rows/wave ----------------
// Block: 128 threads (2 waves x 32 q-rows = 64 q), 16 KV-tiles of 64 keys.
// Swapped QK^T: mfma(A=K, B=Q[qg]) -> D[key][q]; each A-fragment read feeds both
// q-groups (halves LDS bytes per q-row vs 16q/wave). K/KK/VT staged via
// gload_lds (4 calls/buffer, rows c*16+, swizzle preserved since 16%8==0).
__global__ __launch_bounds__(128, 2) void attn_kernel(const short* __restrict__ Qb,
                                                      const short* __restrict__ Kb,
                                                      const short* __restrict__ KK,
                                                      const short* __restrict__ VT,
                                                      float* __restrict__ out) {
    __shared__ short Kt[4096];    // [64 key][64 d], 16B-unit col ^ (row&7)
    __shared__ short KKt[4096];
    __shared__ short VTt[4096];   // [64 d][64 key], same swizzle
    __shared__ short qq[64][72];
    __shared__ short Plds[2][32][72];  // per-wave P: [q][key], padded rows
    int dd = blockIdx.x;
    int xcd = dd & 7, rr = dd >> 3;
    int r0 = (rr & 15) * 64;
    int bh = (rr >> 4) * 8 + xcd;
    int t = threadIdx.x, w = t >> 6, l = t & 63, lr = l & 15, lg = l >> 4;
    const short* qp = Qb + (size_t)bh * 65536;
    const short* kp = Kb + (size_t)bh * 65536;
    const short* kk = KK + (size_t)bh * 65536;
    const short* vt = VT + (size_t)bh * 65536;

    // QQ = -(1/6)*(Qb[n-1]+Qb[n]+Qb[n+1]) for the block's 64 rows (2 passes of 32).
#pragma unroll
    for (int i = 0; i < 2; ++i) {
        int row = i * 32 + (t >> 2), dc = (t & 3) * 16;
        int n = r0 + row;
        const short* src = qp + n * 64 + dc;
        float s[16];
        short8 c0 = *(const short8*)(src), c1 = *(const short8*)(src + 8);
#pragma unroll
        for (int e = 0; e < 8; ++e) { s[e] = b2f(c0[e]); s[8 + e] = b2f(c1[e]); }
        if (n > 0) {
            short8 m0 = *(const short8*)(src - 64), m1 = *(const short8*)(src - 56);
#pragma unroll
            for (int e = 0; e < 8; ++e) { s[e] += b2f(m0[e]); s[8 + e] += b2f(m1[e]); }
        }
        if (n < 1023) {
            short8 p0 = *(const short8*)(src + 64), p1 = *(const short8*)(src + 72);
#pragma unroll
            for (int e = 0; e < 8; ++e) { s[e] += b2f(p0[e]); s[8 + e] += b2f(p1[e]); }
        }
        short8 o0, o1;
#pragma unroll
        for (int e = 0; e < 8; ++e) {
            o0[e] = f2b(-(1.0f / 6.0f) * s[e]);
            o1[e] = f2b(-(1.0f / 6.0f) * s[8 + e]);
        }
        *(short8*)&qq[row][dc] = o0;
        *(short8*)&qq[row][dc + 8] = o1;
    }
    __syncthreads();

    // Q B-operand frags: wave w owns q-rows w*32 .. w*32+31 (2 groups of 16).
    short8 bfr[2][4];
#pragma unroll
    for (int qg = 0; qg < 2; ++qg) {
        int qrow = w * 32 + qg * 16 + lr;
        bfr[qg][0] = *(const short8*)(qp + (r0 + qrow) * 64 + lg * 8);
        bfr[qg][1] = *(const short8*)(qp + (r0 + qrow) * 64 + 32 + lg * 8);
        bfr[qg][2] = *(const short8*)&qq[qrow][lg * 8];
        bfr[qg][3] = *(const short8*)&qq[qrow][32 + lg * 8];
    }

    // Staging: call c covers rows c*16 + (t>>3), 16B col (t&7)^(row&7); linear dest.
    int srow = t >> 3, sc = ((t & 7) ^ (srow & 7)) * 8;
    const short* gk = kp + srow * 64 + sc;
    const short* gkk = kk + srow * 64 + sc;
    const short* gv = vt + srow * 1024 + sc;
    short* pw = &Plds[w][0][0];

    f32x4 O[2][4];
#pragma unroll
    for (int qg = 0; qg < 2; ++qg)
#pragma unroll
        for (int m = 0; m < 4; ++m) O[qg][m] = (f32x4){0.f, 0.f, 0.f, 0.f};
    float m_run0 = -1e30f, l_run0 = 0.f;
    float m_run1 = -1e30f, l_run1 = 0.f;

    for (int tt = 0; tt < 16; ++tt) {
        int ko = tt * 64;  // key offset
#pragma unroll
        for (int c = 0; c < 4; ++c) {
            gload_lds16(gk + ko * 64 + c * 1024, Kt + c * 1024 + w * 512);
            gload_lds16(gkk + ko * 64 + c * 1024, KKt + c * 1024 + w * 512);
            gload_lds16(gv + ko + c * 16384, VTt + c * 1024 + w * 512);
        }
        __syncthreads();  // drains vmcnt: staging complete

        // QK^T: D[key][q], 64 keys x 32 q per wave; A-frags shared by both q-groups.
        f32x4 sacc[2][4];
        __builtin_amdgcn_s_setprio(1);
#pragma unroll
        for (int ct = 0; ct < 4; ++ct) {
            int r = ct * 16 + lr, rs = r * 64, rx = r & 7;
            short8 a0 = *(short8*)&Kt[rs + (((0 + lg) ^ rx) << 3)];
            short8 a1 = *(short8*)&Kt[rs + (((4 + lg) ^ rx) << 3)];
            short8 a2 = *(short8*)&KKt[rs + (((0 + lg) ^ rx) << 3)];
            short8 a3 = *(short8*)&KKt[rs + (((4 + lg) ^ rx) << 3)];
#pragma unroll
            for (int qg = 0; qg < 2; ++qg) {
                f32x4 s_ = (f32x4){0.f, 0.f, 0.f, 0.f};
                s_ = MFMA16(a0, bfr[qg][0], s_);
                s_ = MFMA16(a1, bfr[qg][1], s_);
                s_ = MFMA16(a2, bfr[qg][2], s_);
                s_ = MFMA16(a3, bfr[qg][3], s_);
                sacc[qg][ct] = s_;
            }
        }
        __builtin_amdgcn_s_setprio(0);

        // Online softmax per q-group (q lane-local; keys split across lg).
#pragma unroll
        for (int qg = 0; qg < 2; ++qg) {
            float& m_run = qg ? m_run1 : m_run0;
            float& l_run = qg ? l_run1 : l_run0;
            float mt_ = fmaxf(
                fmaxf(fmaxf(sacc[qg][0][0], sacc[qg][0][1]), fmaxf(sacc[qg][0][2], sacc[qg][0][3])),
                fmaxf(fmaxf(sacc[qg][1][0], sacc[qg][1][1]), fmaxf(sacc[qg][1][2], sacc[qg][1][3])));
            float mt2 = fmaxf(
                fmaxf(fmaxf(sacc[qg][2][0], sacc[qg][2][1]), fmaxf(sacc[qg][2][2], sacc[qg][2][3])),
                fmaxf(fmaxf(sacc[qg][3][0], sacc[qg][3][1]), fmaxf(sacc[qg][3][2], sacc[qg][3][3])));
            mt_ = fmaxf(mt_, mt2);
            mt_ = fmaxf(mt_, __shfl_xor(mt_, 16));
            mt_ = fmaxf(mt_, __shfl_xor(mt_, 32));
            if (__any(mt_ > m_run + 8.0f)) {
                float mnew = fmaxf(m_run, mt_);
                float sc_ = __builtin_amdgcn_exp2f(m_run - mnew);
                m_run = mnew;
                l_run *= sc_;
#pragma unroll
                for (int m = 0; m < 4; ++m)
#pragma unroll
                    for (int i = 0; i < 4; ++i) O[qg][m][i] *= sc_;
            }
            float ps = 0.f;
            short* pwr = pw + (qg * 16 + lr) * 72;
#pragma unroll
            for (int ct = 0; ct < 4; ++ct) {
                float p0 = __builtin_amdgcn_exp2f(sacc[qg][ct][0] - m_run);
                float p1 = __builtin_amdgcn_exp2f(sacc[qg][ct][1] - m_run);
                float p2 = __builtin_amdgcn_exp2f(sacc[qg][ct][2] - m_run);
                float p3 = __builtin_amdgcn_exp2f(sacc[qg][ct][3] - m_run);
                ps += (p0 + p1) + (p2 + p3);
                uint2 wv;
                wv.x = pk2(p0, p1);
                wv.y = pk2(p2, p3);
                *(uint2*)&pwr[ct * 16 + lg * 4] = wv;
            }
            l_run += ps;
        }

        // PV: O^T[d][q] += VT-tile . P[qg]; VT-frags shared by both q-groups.
        short8 pb[2][2];
#pragma unroll
        for (int qg = 0; qg < 2; ++qg) {
            short* pwr = pw + (qg * 16 + lr) * 72;
            pb[qg][0] = *(short8*)&pwr[lg * 8];
            pb[qg][1] = *(short8*)&pwr[32 + lg * 8];
        }
        __builtin_amdgcn_s_setprio(1);
#pragma unroll
        for (int m = 0; m < 4; ++m) {
            int r = m * 16 + lr, rs = r * 64, rx = r & 7;
            short8 v0 = *(short8*)&VTt[rs + (((0 + lg) ^ rx) << 3)];
            short8 v1 = *(short8*)&VTt[rs + (((4 + lg) ^ rx) << 3)];
#pragma unroll
            for (int qg = 0; qg < 2; ++qg) {
                O[qg][m] = MFMA16(v0, pb[qg][0], O[qg][m]);
                O[qg][m] = MFMA16(v1, pb[qg][1], O[qg][m]);
            }
        }
        __builtin_amdgcn_s_setprio(0);
        __syncthreads();  // all waves done reading tile before next stage
    }

    int b = bh / 12, h = bh - b * 12;
#pragma unroll
    for (int qg = 0; qg < 2; ++qg) {
        float l_run = qg ? l_run1 : l_run0;
        l_run += __shfl_xor(l_run, 16);
        l_run += __shfl_xor(l_run, 32);
        float inv = 1.f / l_run;
        int q = r0 + w * 32 + qg * 16 + lr;
        float* ob = out + (size_t)(b * 1024 + q) * 768 + h * 64;
#pragma unroll
        for (int m = 0; m < 4; ++m) {
            float4 o4;
            o4.x = O[qg][m][0] * inv; o4.y = O[qg][m][1] * inv;
            o4.z = O[qg][m][2] * inv; o4.w = O[qg][m][3] * inv;
            *(float4*)(ob + m * 16 + lg * 4) = o4;
        }
    }
}

extern "C" void kernel_launch(void* const* d_in, const int* in_sizes, int n_in,
                              void* d_out, int out_size, void* d_ws, size_t ws_size,
                              hipStream_t stream) {
    const float* x  = (const float*)d_in[0];
    const float* W  = (const float*)d_in[1];
    const float* qb = (const float*)d_in[2];
    const float* lg = (const float*)d_in[3];
    const float* lb = (const float*)d_in[4];
    float* out = (float*)d_out;
    char* ws = (char*)d_ws;
    // Workspace layout (peak 28,704,768 bytes):
    short* xnb = (short*)(ws + 0);         // [4096][768] bf16 (dead after gemm)
    short* Wb  = (short*)(ws + 6291456);   // [2304][768] bf16
    short* Qb  = (short*)(ws + 9830400);   // [48][1024][64] bf16, pre-scaled by cq*log2e
    short* Kb  = (short*)(ws + 16121856);  // [48][1024][64] bf16
    short* VT  = (short*)(ws + 22413312);  // [48][64][1024] bf16
    short* KK  = (short*)(ws + 0);         // [48][1024][64] bf16, overlays dead xnb

    hipLaunchKernelGGL(prep_kernel, dim3(5824), dim3(256), 0, stream, x, lg, lb, W, xnb, Wb);
    hipLaunchKernelGGL(qkv_gemm, dim3(32, 18), dim3(256), 0, stream, xnb, Wb, qb, Qb, Kb, VT);
    hipLaunchKernelGGL(kk_kernel, dim3(32, 48), dim3(256), 0, stream, Kb, KK);
    hipLaunchKernelGGL(attn_kernel, dim3(768), dim3(128), 0, stream, Qb, Kb, KK, VT, out);
}

// Round 14
// 81.606 us; speedup vs baseline: 1.1198x; 1.1198x over previous
//
#include <hip/hip_runtime.h>

// LateralInhibitionAttention, MI355X.
// Conv3x3 of the rank-structured score matrix factorizes:
//   sum_{3x3} s[n+i][m+j] = (q[n-1]+q[n]+q[n+1]) . (k[m-1]+k[m]+k[m+1])
// so inhibited scores = [cq*q ; cs*qsum] . [k ; ksum]  (augmented 128-dim dot).
// R13 post-mortem: 32q/wave attn regressed (occ 12.7%, TLP collapse; LDS-BW
// theory falsified) -> attn reverted to R12-proven form.
// R14: qkv_gemm grid starvation fix: 64x128 tiles -> grid 1152 (4.5 blk/CU vs
// 2.25), 12.3KB LDS, acc[4][2]/wave. Same staging pattern, adapted epilogues.

using short8 = __attribute__((ext_vector_type(8))) short;
using short4v = __attribute__((ext_vector_type(4))) short;
using f32x4 = __attribute__((ext_vector_type(4))) float;

#define MFMA16(a, b, c) __builtin_amdgcn_mfma_f32_16x16x32_bf16((a), (b), (c), 0, 0, 0)

__device__ __forceinline__ float b2f(short s) {
    union { unsigned u; float f; } x;
    x.u = ((unsigned)(unsigned short)s) << 16;
    return x.f;
}
__device__ __forceinline__ short f2b(float f) {  // RNE f32->bf16
    unsigned u = __float_as_uint(f);
    unsigned r = (u + 0x7FFFu + ((u >> 16) & 1u)) >> 16;
    return (short)r;
}
__device__ __forceinline__ unsigned pk2(float lo, float hi) {  // packed bf16x2, 1 VALU op
    unsigned r;
    asm("v_cvt_pk_bf16_f32 %0, %1, %2" : "=v"(r) : "v"(lo), "v"(hi));
    return r;
}
// async global->LDS, 16B per lane; lds dest must be wave-uniform base (+lane*16 implicit)
__device__ __forceinline__ void gload_lds16(const short* g, short* l) {
    __builtin_amdgcn_global_load_lds(
        (const __attribute__((address_space(1))) void*)g,
        (__attribute__((address_space(3))) void*)l, 16, 0, 0);
}

// ---------------- fused LayerNorm->bf16 (blocks 0..4095) + W->bf16 (4096..5823) ----------------
__global__ __launch_bounds__(256) void prep_kernel(const float* __restrict__ x,
                                                   const float* __restrict__ g,
                                                   const float* __restrict__ bb,
                                                   const float* __restrict__ W,
                                                   short* __restrict__ xnb,
                                                   short* __restrict__ Wb) {
    int bid = blockIdx.x, t = threadIdx.x;
    if (bid >= 4096) {  // W f32 -> bf16 chunk
        int i = ((bid - 4096) * 256 + t) * 4;
        float4 v = *(const float4*)(W + i);
        short4v o;
        o[0] = f2b(v.x); o[1] = f2b(v.y); o[2] = f2b(v.z); o[3] = f2b(v.w);
        *(short4v*)(Wb + i) = o;
        return;
    }
    int row = bid;
    const float* xr = x + (size_t)row * 768;
    float v0 = xr[t], v1 = xr[t + 256], v2 = xr[t + 512];
    float s = v0 + v1 + v2;
    float ss = v0 * v0 + v1 * v1 + v2 * v2;
#pragma unroll
    for (int o = 1; o < 64; o <<= 1) { s += __shfl_xor(s, o); ss += __shfl_xor(ss, o); }
    __shared__ float red[8];
    int w = t >> 6;
    if ((t & 63) == 0) { red[w] = s; red[4 + w] = ss; }
    __syncthreads();
    s = red[0] + red[1] + red[2] + red[3];
    ss = red[4] + red[5] + red[6] + red[7];
    float mu = s * (1.0f / 768.0f);
    float var = ss * (1.0f / 768.0f) - mu * mu;
    float rs = rsqrtf(var + 1e-5f);
    short* o = xnb + (size_t)row * 768;
    o[t]       = f2b((v0 - mu) * rs * g[t]       + bb[t]);
    o[t + 256] = f2b((v1 - mu) * rs * g[t + 256] + bb[t + 256]);
    o[t + 512] = f2b((v2 - mu) * rs * g[t + 512] + bb[t + 512]);
}

// ---------------- QKV GEMM: [4096,768]x[768,2304]^T, 64x128 tiles ----------------
// Grid (64,18) = 1152 blocks (4.5/CU), 4 waves, each wave 64 rows x 32 cols.
// blockIdx.y 0-5: Q (scaled cq*log2e), 6-11: K, 12-17: V -> VT via LDS transpose.
__global__ __launch_bounds__(256) void qkv_gemm(const short* __restrict__ A,
                                                const short* __restrict__ B,
                                                const float* __restrict__ bias,
                                                short* __restrict__ Qb,
                                                short* __restrict__ Kb,
                                                short* __restrict__ VT) {
    __shared__ char smem[12288];
    short* As = (short*)smem;            // [64][32] bf16
    short* Bs = (short*)(smem + 4096);   // [128][32] bf16
    int t = threadIdx.x, w = t >> 6, l = t & 63, lr = l & 15, lg = l >> 4;
    int row0 = blockIdx.x * 64;
    int col0 = blockIdx.y * 128;
    const short* agp  = A + (size_t)(row0 + (t >> 2)) * 768 + (t & 3) * 8;
    const short* bgp0 = B + (size_t)(col0 + (t >> 2)) * 768 + (t & 3) * 8;
    const short* bgp1 = bgp0 + (size_t)64 * 768;
    short* asl  = As + (w * 64) * 8;
    short* bsl0 = Bs + (w * 64) * 8;
    short* bsl1 = Bs + (256 + w * 64) * 8;

    f32x4 acc[4][2];
#pragma unroll
    for (int m = 0; m < 4; ++m)
#pragma unroll
        for (int n = 0; n < 2; ++n) acc[m][n] = (f32x4){0.f, 0.f, 0.f, 0.f};

    for (int k0 = 0; k0 < 768; k0 += 32) {
        gload_lds16(agp + k0, asl);
        gload_lds16(bgp0 + k0, bsl0);
        gload_lds16(bgp1 + k0, bsl1);
        __syncthreads();
        short8 af[4], bf[2];
#pragma unroll
        for (int m = 0; m < 4; ++m)
            af[m] = *(short8*)&As[(m * 16 + lr) * 32 + lg * 8];
#pragma unroll
        for (int n = 0; n < 2; ++n)
            bf[n] = *(short8*)&Bs[(w * 32 + n * 16 + lr) * 32 + lg * 8];
#pragma unroll
        for (int m = 0; m < 4; ++m)
#pragma unroll
            for (int n = 0; n < 2; ++n)
                acc[m][n] = MFMA16(af[m], bf[n], acc[m][n]);
        __syncthreads();
    }

    int sec = blockIdx.y / 6;  // uniform per block
    if (sec < 2) {
        short* dst = sec ? Kb : Qb;
        // Q pre-scale: 1.2 * D^-0.5 * log2(e)  -> scores arrive in log2 space.
        const float scl = sec ? 1.0f : (1.2f * 0.125f * 1.44269504088896f);
#pragma unroll
        for (int n = 0; n < 2; ++n) {
            int j = col0 + w * 32 + n * 16 + lr;
            float bs = bias[j];
            int jj = j - sec * 768;
            int h = jj >> 6, d = jj & 63;
#pragma unroll
            for (int m = 0; m < 4; ++m)
#pragma unroll
                for (int i = 0; i < 4; ++i) {
                    int row = row0 + m * 16 + lg * 4 + i;
                    int b = row >> 10, n_ = row & 1023;
                    dst[(size_t)(((b * 12 + h) << 10) | n_) * 64 + d] =
                        f2b(scl * (acc[m][n][i] + bs));
                }
        }
    } else {
        // V: transpose 64x128 tile -> VT[d][n], two 64-col passes through LDS.
        short* tr = (short*)smem;  // [64 cols][72]
        int b = row0 >> 10, nin = row0 & 1023;
        int jj0 = col0 - 1536;
        for (int p = 0; p < 2; ++p) {
            __syncthreads();
            if ((w >> 1) == p) {   // waves 2p,2p+1 own cols p*64..p*64+63
#pragma unroll
                for (int n = 0; n < 2; ++n) {
                    int jl = (w & 1) * 32 + n * 16 + lr;
                    float bs = bias[col0 + p * 64 + jl];
#pragma unroll
                    for (int m = 0; m < 4; ++m) {
                        int nl = m * 16 + lg * 4;
                        short4v o;
#pragma unroll
                        for (int i = 0; i < 4; ++i) o[i] = f2b(acc[m][n][i] + bs);
                        *(short4v*)&tr[jl * 72 + nl] = o;
                    }
                }
            }
            __syncthreads();
            int jl2 = t >> 2, qd = t & 3;
            int j = jj0 + p * 64 + jl2;
            int h = j >> 6, d = j & 63;
            short* vtb = VT + (size_t)(b * 12 + h) * 65536 + d * 1024 + nin + qd * 16;
            *(short8*)(vtb)     = *(short8*)&tr[jl2 * 72 + qd * 16];
            *(short8*)(vtb + 8) = *(short8*)&tr[jl2 * 72 + qd * 16 + 8];
        }
    }
}

// ---------------- KK = k[n-1]+k[n]+k[n+1] (zero-padded) ----------------
__global__ __launch_bounds__(256) void kk_kernel(const short* __restrict__ Kb,
                                                 short* __restrict__ KK) {
    int bh = blockIdx.y;
    int t = threadIdx.x;
    int n = blockIdx.x * 32 + (t >> 3), dc = (t & 7) * 8;
    const short* kp = Kb + (size_t)bh * 65536;
    float s[8];
    short8 c = *(const short8*)(kp + n * 64 + dc);
#pragma unroll
    for (int e = 0; e < 8; ++e) s[e] = b2f(c[e]);
    if (n > 0) {
        short8 m = *(const short8*)(kp + (n - 1) * 64 + dc);
#pragma unroll
        for (int e = 0; e < 8; ++e) s[e] += b2f(m[e]);
    }
    if (n < 1023) {
        short8 p = *(const short8*)(kp + (n + 1) * 64 + dc);
#pragma unroll
        for (int e = 0; e < 8; ++e) s[e] += b2f(p[e]);
    }
    short8 o;
#pragma unroll
    for (int e = 0; e < 8; ++e) o[e] = f2b(s[e]);
    *(short8*)(KK + (size_t)bh * 65536 + n * 64 + dc) = o;
}

// ---------------- flash attention: online softmax (log2-space), no S buffer ----------------
// Block: 64 q-rows (4 waves x 16), loop over 16 KV-tiles of 64 keys.
// Swapped QK^T: mfma(A=K, B=Q) -> D[key][q], q = lane&15 (lane-local stats).
// K/KK/VT tiles staged via global_load_lds with XOR-16B-unit swizzle.
// PV: mfma(A=VT, B=P) -> O^T[d][q]; normalize once at the end.  (R12-proven form.)
__global__ __launch_bounds__(256, 3) void attn_kernel(const short* __restrict__ Qb,
                                                      const short* __restrict__ Kb,
                                                      const short* __restrict__ KK,
                                                      const short* __restrict__ VT,
                                                      float* __restrict__ out) {
    __shared__ short Kt[4096];    // [64 key][64 d], 16B-unit col ^ (row&7)
    __shared__ short KKt[4096];
    __shared__ short VTt[4096];   // [64 d][64 key], same swizzle
    __shared__ short qq[64][72];
    __shared__ short Plds[4][16][72];  // per-wave P: [q][key], padded rows
    int dd = blockIdx.x;
    int xcd = dd & 7, rr = dd >> 3;
    int r0 = (rr & 15) * 64;
    int bh = (rr >> 4) * 8 + xcd;
    int t = threadIdx.x, w = t >> 6, l = t & 63, lr = l & 15, lg = l >> 4;
    const short* qp = Qb + (size_t)bh * 65536;
    const short* kp = Kb + (size_t)bh * 65536;
    const short* kk = KK + (size_t)bh * 65536;
    const short* vt = VT + (size_t)bh * 65536;

    // QQ = -(1/6)*(Qb[n-1]+Qb[n]+Qb[n+1]) for the block's 64 rows.
    {
        int row = t >> 2, dc = (t & 3) * 16;
        int n = r0 + row;
        const short* src = qp + n * 64 + dc;
        float s[16];
        short8 c0 = *(const short8*)(src), c1 = *(const short8*)(src + 8);
#pragma unroll
        for (int e = 0; e < 8; ++e) { s[e] = b2f(c0[e]); s[8 + e] = b2f(c1[e]); }
        if (n > 0) {
            short8 m0 = *(const short8*)(src - 64), m1 = *(const short8*)(src - 56);
#pragma unroll
            for (int e = 0; e < 8; ++e) { s[e] += b2f(m0[e]); s[8 + e] += b2f(m1[e]); }
        }
        if (n < 1023) {
            short8 p0 = *(const short8*)(src + 64), p1 = *(const short8*)(src + 72);
#pragma unroll
            for (int e = 0; e < 8; ++e) { s[e] += b2f(p0[e]); s[8 + e] += b2f(p1[e]); }
        }
        short8 o0, o1;
#pragma unroll
        for (int e = 0; e < 8; ++e) {
            o0[e] = f2b(-(1.0f / 6.0f) * s[e]);
            o1[e] = f2b(-(1.0f / 6.0f) * s[8 + e]);
        }
        *(short8*)&qq[row][dc] = o0;
        *(short8*)&qq[row][dc + 8] = o1;
    }
    __syncthreads();

    // Q B-operand frags for this wave's 16 q-rows (K=128 augmented).
    short8 bfr[4];
    bfr[0] = *(const short8*)(qp + (r0 + w * 16 + lr) * 64 + lg * 8);
    bfr[1] = *(const short8*)(qp + (r0 + w * 16 + lr) * 64 + 32 + lg * 8);
    bfr[2] = *(const short8*)&qq[w * 16 + lr][lg * 8];
    bfr[3] = *(const short8*)&qq[w * 16 + lr][32 + lg * 8];

    // Staging: unit u covers rows (u>>3), 16B col (u&7); source pre-swizzled.
    int srow = t >> 3, sc = ((t & 7) ^ (srow & 7)) * 8;
    const short* gk = kp + srow * 64 + sc;       // +2048 shorts for second half
    const short* gkk = kk + srow * 64 + sc;
    const short* gv = vt + srow * 1024 + sc;     // +32768 for second half
    short* dk0 = Kt + w * 512;   short* dk1 = Kt + 2048 + w * 512;
    short* dkk0 = KKt + w * 512; short* dkk1 = KKt + 2048 + w * 512;
    short* dv0 = VTt + w * 512;  short* dv1 = VTt + 2048 + w * 512;
    short* pw = &Plds[w][0][0];
    short* pwr = pw + lr * 72;

    f32x4 O[4];
#pragma unroll
    for (int m = 0; m < 4; ++m) O[m] = (f32x4){0.f, 0.f, 0.f, 0.f};
    float m_run = -1e30f, l_run = 0.f;

    for (int tt = 0; tt < 16; ++tt) {
        int ko = tt * 64;  // key offset
        gload_lds16(gk + ko * 64, dk0);
        gload_lds16(gk + ko * 64 + 2048, dk1);
        gload_lds16(gkk + ko * 64, dkk0);
        gload_lds16(gkk + ko * 64 + 2048, dkk1);
        gload_lds16(gv + ko, dv0);
        gload_lds16(gv + ko + 32768, dv1);
        __syncthreads();  // drains vmcnt: staging complete

        // QK^T: D[key][q] (log2-space scores), 64 keys x 16 q per wave.
        f32x4 sacc[4];
        __builtin_amdgcn_s_setprio(1);
#pragma unroll
        for (int ct = 0; ct < 4; ++ct) {
            int r = ct * 16 + lr, rs = r * 64, rx = r & 7;
            short8 a0 = *(short8*)&Kt[rs + (((0 + lg) ^ rx) << 3)];
            short8 a1 = *(short8*)&Kt[rs + (((4 + lg) ^ rx) << 3)];
            short8 a2 = *(short8*)&KKt[rs + (((0 + lg) ^ rx) << 3)];
            short8 a3 = *(short8*)&KKt[rs + (((4 + lg) ^ rx) << 3)];
            f32x4 s_ = (f32x4){0.f, 0.f, 0.f, 0.f};
            s_ = MFMA16(a0, bfr[0], s_);
            s_ = MFMA16(a1, bfr[1], s_);
            s_ = MFMA16(a2, bfr[2], s_);
            s_ = MFMA16(a3, bfr[3], s_);
            sacc[ct] = s_;
        }
        __builtin_amdgcn_s_setprio(0);
        // Online softmax in log2 space (q = lr lane-local; keys split across lg).
        float mt_ = fmaxf(fmaxf(fmaxf(sacc[0][0], sacc[0][1]), fmaxf(sacc[0][2], sacc[0][3])),
                          fmaxf(fmaxf(sacc[1][0], sacc[1][1]), fmaxf(sacc[1][2], sacc[1][3])));
        float mt2 = fmaxf(fmaxf(fmaxf(sacc[2][0], sacc[2][1]), fmaxf(sacc[2][2], sacc[2][3])),
                          fmaxf(fmaxf(sacc[3][0], sacc[3][1]), fmaxf(sacc[3][2], sacc[3][3])));
        mt_ = fmaxf(mt_, mt2);
        mt_ = fmaxf(mt_, __shfl_xor(mt_, 16));
        mt_ = fmaxf(mt_, __shfl_xor(mt_, 32));
        // Defer-max: only rescale when the tile max pushes past m_run + 8.
        if (__any(mt_ > m_run + 8.0f)) {
            float mnew = fmaxf(m_run, mt_);
            float sc_ = __builtin_amdgcn_exp2f(m_run - mnew);
            m_run = mnew;
            l_run *= sc_;
#pragma unroll
            for (int m = 0; m < 4; ++m)
#pragma unroll
                for (int i = 0; i < 4; ++i) O[m][i] *= sc_;
        }
        float ps = 0.f;
#pragma unroll
        for (int ct = 0; ct < 4; ++ct) {
            float p0 = __builtin_amdgcn_exp2f(sacc[ct][0] - m_run);
            float p1 = __builtin_amdgcn_exp2f(sacc[ct][1] - m_run);
            float p2 = __builtin_amdgcn_exp2f(sacc[ct][2] - m_run);
            float p3 = __builtin_amdgcn_exp2f(sacc[ct][3] - m_run);
            ps += (p0 + p1) + (p2 + p3);
            uint2 wv;
            wv.x = pk2(p0, p1);
            wv.y = pk2(p2, p3);
            *(uint2*)&pwr[ct * 16 + lg * 4] = wv;
        }
        l_run += ps;
        // PV: O^T[d][q] += VT-tile . P-tile
        short8 pb0 = *(short8*)&pwr[lg * 8];
        short8 pb1 = *(short8*)&pwr[32 + lg * 8];
        __builtin_amdgcn_s_setprio(1);
#pragma unroll
        for (int m = 0; m < 4; ++m) {
            int r = m * 16 + lr, rs = r * 64, rx = r & 7;
            short8 v0 = *(short8*)&VTt[rs + (((0 + lg) ^ rx) << 3)];
            short8 v1 = *(short8*)&VTt[rs + (((4 + lg) ^ rx) << 3)];
            O[m] = MFMA16(v0, pb0, O[m]);
            O[m] = MFMA16(v1, pb1, O[m]);
        }
        __builtin_amdgcn_s_setprio(0);
        __syncthreads();  // all waves done reading tile before next stage
    }

    l_run += __shfl_xor(l_run, 16);
    l_run += __shfl_xor(l_run, 32);
    float inv = 1.f / l_run;
    int b = bh / 12, h = bh - b * 12;
    int q = r0 + w * 16 + lr;
    float* ob = out + (size_t)(b * 1024 + q) * 768 + h * 64;
#pragma unroll
    for (int m = 0; m < 4; ++m) {
        float4 o4;
        o4.x = O[m][0] * inv; o4.y = O[m][1] * inv;
        o4.z = O[m][2] * inv; o4.w = O[m][3] * inv;
        *(float4*)(ob + m * 16 + lg * 4) = o4;
    }
}

extern "C" void kernel_launch(void* const* d_in, const int* in_sizes, int n_in,
                              void* d_out, int out_size, void* d_ws, size_t ws_size,
                              hipStream_t stream) {
    const float* x  = (const float*)d_in[0];
    const float* W  = (const float*)d_in[1];
    const float* qb = (const float*)d_in[2];
    const float* lg = (const float*)d_in[3];
    const float* lb = (const float*)d_in[4];
    float* out = (float*)d_out;
    char* ws = (char*)d_ws;
    // Workspace layout (peak 28,704,768 bytes):
    short* xnb = (short*)(ws + 0);         // [4096][768] bf16 (dead after gemm)
    short* Wb  = (short*)(ws + 6291456);   // [2304][768] bf16
    short* Qb  = (short*)(ws + 9830400);   // [48][1024][64] bf16, pre-scaled by cq*log2e
    short* Kb  = (short*)(ws + 16121856);  // [48][1024][64] bf16
    short* VT  = (short*)(ws + 22413312);  // [48][64][1024] bf16
    short* KK  = (short*)(ws + 0);         // [48][1024][64] bf16, overlays dead xnb

    hipLaunchKernelGGL(prep_kernel, dim3(5824), dim3(256), 0, stream, x, lg, lb, W, xnb, Wb);
    hipLaunchKernelGGL(qkv_gemm, dim3(64, 18), dim3(256), 0, stream, xnb, Wb, qb, Qb, Kb, VT);
    hipLaunchKernelGGL(kk_kernel, dim3(32, 48), dim3(256), 0, stream, Kb, KK);
    hipLaunchKernelGGL(attn_kernel, dim3(768), dim3(256), 0, stream, Qb, Kb, KK, VT, out);
}

// Round 15
// 80.801 us; speedup vs baseline: 1.1309x; 1.0100x over previous
//
#include <hip/hip_runtime.h>

// LateralInhibitionAttention, MI355X.
// Conv3x3 of the rank-structured score matrix factorizes:
//   sum_{3x3} s[n+i][m+j] = (q[n-1]+q[n]+q[n+1]) . (k[m-1]+k[m]+k[m+1])
// so inhibited scores = [cq*q ; cs*qsum] . [k ; ksum]  (augmented 128-dim dot).
// R14: 64x128 gemm tiles fixed grid starvation (86.9 -> 81.6us).
// R15 (overhead trims): (1) LN -> wave-per-row (no LDS/barrier, 4 rows/block);
// (2) attn computes the -1/6*Q-neighbor-sum fragments per-lane from global,
// dropping the qq LDS stage + one barrier (LDS 43 -> 33.8KB).

using short8 = __attribute__((ext_vector_type(8))) short;
using short4v = __attribute__((ext_vector_type(4))) short;
using f32x4 = __attribute__((ext_vector_type(4))) float;

#define MFMA16(a, b, c) __builtin_amdgcn_mfma_f32_16x16x32_bf16((a), (b), (c), 0, 0, 0)

__device__ __forceinline__ float b2f(short s) {
    union { unsigned u; float f; } x;
    x.u = ((unsigned)(unsigned short)s) << 16;
    return x.f;
}
__device__ __forceinline__ short f2b(float f) {  // RNE f32->bf16
    unsigned u = __float_as_uint(f);
    unsigned r = (u + 0x7FFFu + ((u >> 16) & 1u)) >> 16;
    return (short)r;
}
__device__ __forceinline__ unsigned pk2(float lo, float hi) {  // packed bf16x2, 1 VALU op
    unsigned r;
    asm("v_cvt_pk_bf16_f32 %0, %1, %2" : "=v"(r) : "v"(lo), "v"(hi));
    return r;
}
// async global->LDS, 16B per lane; lds dest must be wave-uniform base (+lane*16 implicit)
__device__ __forceinline__ void gload_lds16(const short* g, short* l) {
    __builtin_amdgcn_global_load_lds(
        (const __attribute__((address_space(1))) void*)g,
        (__attribute__((address_space(3))) void*)l, 16, 0, 0);
}

// -------- prep: LN->bf16 wave-per-row (blocks 0..1023, 4 rows each) + W->bf16 (1024..2751) --------
__global__ __launch_bounds__(256) void prep_kernel(const float* __restrict__ x,
                                                   const float* __restrict__ g,
                                                   const float* __restrict__ bb,
                                                   const float* __restrict__ W,
                                                   short* __restrict__ xnb,
                                                   short* __restrict__ Wb) {
    int bid = blockIdx.x, t = threadIdx.x;
    if (bid >= 1024) {  // W f32 -> bf16 chunk
        int i = ((bid - 1024) * 256 + t) * 4;
        float4 v = *(const float4*)(W + i);
        short4v o;
        o[0] = f2b(v.x); o[1] = f2b(v.y); o[2] = f2b(v.z); o[3] = f2b(v.w);
        *(short4v*)(Wb + i) = o;
        return;
    }
    int w = t >> 6, l = t & 63;
    int row = bid * 4 + w;
    const float* xr = x + (size_t)row * 768;
    float4 a = *(const float4*)(xr + l * 4);
    float4 b = *(const float4*)(xr + 256 + l * 4);
    float4 c = *(const float4*)(xr + 512 + l * 4);
    float s = (a.x + a.y + a.z + a.w) + (b.x + b.y + b.z + b.w) + (c.x + c.y + c.z + c.w);
    float ss = (a.x * a.x + a.y * a.y + a.z * a.z + a.w * a.w) +
               (b.x * b.x + b.y * b.y + b.z * b.z + b.w * b.w) +
               (c.x * c.x + c.y * c.y + c.z * c.z + c.w * c.w);
#pragma unroll
    for (int o = 1; o < 64; o <<= 1) { s += __shfl_xor(s, o); ss += __shfl_xor(ss, o); }
    float mu = s * (1.0f / 768.0f);
    float var = ss * (1.0f / 768.0f) - mu * mu;
    float rs = rsqrtf(var + 1e-5f);
    float4 ga = *(const float4*)(g + l * 4);
    float4 gb = *(const float4*)(g + 256 + l * 4);
    float4 gc = *(const float4*)(g + 512 + l * 4);
    float4 ba = *(const float4*)(bb + l * 4);
    float4 bg = *(const float4*)(bb + 256 + l * 4);
    float4 bc = *(const float4*)(bb + 512 + l * 4);
    short* o = xnb + (size_t)row * 768;
    short4v o0, o1, o2;
    o0[0] = f2b((a.x - mu) * rs * ga.x + ba.x);
    o0[1] = f2b((a.y - mu) * rs * ga.y + ba.y);
    o0[2] = f2b((a.z - mu) * rs * ga.z + ba.z);
    o0[3] = f2b((a.w - mu) * rs * ga.w + ba.w);
    o1[0] = f2b((b.x - mu) * rs * gb.x + bg.x);
    o1[1] = f2b((b.y - mu) * rs * gb.y + bg.y);
    o1[2] = f2b((b.z - mu) * rs * gb.z + bg.z);
    o1[3] = f2b((b.w - mu) * rs * gb.w + bg.w);
    o2[0] = f2b((c.x - mu) * rs * gc.x + bc.x);
    o2[1] = f2b((c.y - mu) * rs * gc.y + bc.y);
    o2[2] = f2b((c.z - mu) * rs * gc.z + bc.z);
    o2[3] = f2b((c.w - mu) * rs * gc.w + bc.w);
    *(short4v*)(o + l * 4) = o0;
    *(short4v*)(o + 256 + l * 4) = o1;
    *(short4v*)(o + 512 + l * 4) = o2;
}

// ---------------- QKV GEMM: [4096,768]x[768,2304]^T, 64x128 tiles (R14-proven) ----------------
__global__ __launch_bounds__(256) void qkv_gemm(const short* __restrict__ A,
                                                const short* __restrict__ B,
                                                const float* __restrict__ bias,
                                                short* __restrict__ Qb,
                                                short* __restrict__ Kb,
                                                short* __restrict__ VT) {
    __shared__ char smem[12288];
    short* As = (short*)smem;            // [64][32] bf16
    short* Bs = (short*)(smem + 4096);   // [128][32] bf16
    int t = threadIdx.x, w = t >> 6, l = t & 63, lr = l & 15, lg = l >> 4;
    int row0 = blockIdx.x * 64;
    int col0 = blockIdx.y * 128;
    const short* agp  = A + (size_t)(row0 + (t >> 2)) * 768 + (t & 3) * 8;
    const short* bgp0 = B + (size_t)(col0 + (t >> 2)) * 768 + (t & 3) * 8;
    const short* bgp1 = bgp0 + (size_t)64 * 768;
    short* asl  = As + (w * 64) * 8;
    short* bsl0 = Bs + (w * 64) * 8;
    short* bsl1 = Bs + (256 + w * 64) * 8;

    f32x4 acc[4][2];
#pragma unroll
    for (int m = 0; m < 4; ++m)
#pragma unroll
        for (int n = 0; n < 2; ++n) acc[m][n] = (f32x4){0.f, 0.f, 0.f, 0.f};

    for (int k0 = 0; k0 < 768; k0 += 32) {
        gload_lds16(agp + k0, asl);
        gload_lds16(bgp0 + k0, bsl0);
        gload_lds16(bgp1 + k0, bsl1);
        __syncthreads();
        short8 af[4], bf[2];
#pragma unroll
        for (int m = 0; m < 4; ++m)
            af[m] = *(short8*)&As[(m * 16 + lr) * 32 + lg * 8];
#pragma unroll
        for (int n = 0; n < 2; ++n)
            bf[n] = *(short8*)&Bs[(w * 32 + n * 16 + lr) * 32 + lg * 8];
#pragma unroll
        for (int m = 0; m < 4; ++m)
#pragma unroll
            for (int n = 0; n < 2; ++n)
                acc[m][n] = MFMA16(af[m], bf[n], acc[m][n]);
        __syncthreads();
    }

    int sec = blockIdx.y / 6;  // uniform per block
    if (sec < 2) {
        short* dst = sec ? Kb : Qb;
        // Q pre-scale: 1.2 * D^-0.5 * log2(e)  -> scores arrive in log2 space.
        const float scl = sec ? 1.0f : (1.2f * 0.125f * 1.44269504088896f);
#pragma unroll
        for (int n = 0; n < 2; ++n) {
            int j = col0 + w * 32 + n * 16 + lr;
            float bs = bias[j];
            int jj = j - sec * 768;
            int h = jj >> 6, d = jj & 63;
#pragma unroll
            for (int m = 0; m < 4; ++m)
#pragma unroll
                for (int i = 0; i < 4; ++i) {
                    int row = row0 + m * 16 + lg * 4 + i;
                    int b = row >> 10, n_ = row & 1023;
                    dst[(size_t)(((b * 12 + h) << 10) | n_) * 64 + d] =
                        f2b(scl * (acc[m][n][i] + bs));
                }
        }
    } else {
        // V: transpose 64x128 tile -> VT[d][n], two 64-col passes through LDS.
        short* tr = (short*)smem;  // [64 cols][72]
        int b = row0 >> 10, nin = row0 & 1023;
        int jj0 = col0 - 1536;
        for (int p = 0; p < 2; ++p) {
            __syncthreads();
            if ((w >> 1) == p) {   // waves 2p,2p+1 own cols p*64..p*64+63
#pragma unroll
                for (int n = 0; n < 2; ++n) {
                    int jl = (w & 1) * 32 + n * 16 + lr;
                    float bs = bias[col0 + p * 64 + jl];
#pragma unroll
                    for (int m = 0; m < 4; ++m) {
                        int nl = m * 16 + lg * 4;
                        short4v o;
#pragma unroll
                        for (int i = 0; i < 4; ++i) o[i] = f2b(acc[m][n][i] + bs);
                        *(short4v*)&tr[jl * 72 + nl] = o;
                    }
                }
            }
            __syncthreads();
            int jl2 = t >> 2, qd = t & 3;
            int j = jj0 + p * 64 + jl2;
            int h = j >> 6, d = j & 63;
            short* vtb = VT + (size_t)(b * 12 + h) * 65536 + d * 1024 + nin + qd * 16;
            *(short8*)(vtb)     = *(short8*)&tr[jl2 * 72 + qd * 16];
            *(short8*)(vtb + 8) = *(short8*)&tr[jl2 * 72 + qd * 16 + 8];
        }
    }
}

// ---------------- KK = k[n-1]+k[n]+k[n+1] (zero-padded) ----------------
__global__ __launch_bounds__(256) void kk_kernel(const short* __restrict__ Kb,
                                                 short* __restrict__ KK) {
    int bh = blockIdx.y;
    int t = threadIdx.x;
    int n = blockIdx.x * 32 + (t >> 3), dc = (t & 7) * 8;
    const short* kp = Kb + (size_t)bh * 65536;
    float s[8];
    short8 c = *(const short8*)(kp + n * 64 + dc);
#pragma unroll
    for (int e = 0; e < 8; ++e) s[e] = b2f(c[e]);
    if (n > 0) {
        short8 m = *(const short8*)(kp + (n - 1) * 64 + dc);
#pragma unroll
        for (int e = 0; e < 8; ++e) s[e] += b2f(m[e]);
    }
    if (n < 1023) {
        short8 p = *(const short8*)(kp + (n + 1) * 64 + dc);
#pragma unroll
        for (int e = 0; e < 8; ++e) s[e] += b2f(p[e]);
    }
    short8 o;
#pragma unroll
    for (int e = 0; e < 8; ++e) o[e] = f2b(s[e]);
    *(short8*)(KK + (size_t)bh * 65536 + n * 64 + dc) = o;
}

// ---------------- flash attention: online softmax (log2-space), no S buffer ----------------
// Block: 64 q-rows (4 waves x 16), loop over 16 KV-tiles of 64 keys.
// Swapped QK^T: mfma(A=K, B=Q) -> D[key][q], q = lane&15 (lane-local stats).
// bfr[2..3] (-1/6 Q-neighbor sums) computed per-lane from global (no qq LDS).
// K/KK/VT tiles staged via global_load_lds with XOR-16B-unit swizzle.
// PV: mfma(A=VT, B=P) -> O^T[d][q]; normalize once at the end.
__global__ __launch_bounds__(256, 3) void attn_kernel(const short* __restrict__ Qb,
                                                      const short* __restrict__ Kb,
                                                      const short* __restrict__ KK,
                                                      const short* __restrict__ VT,
                                                      float* __restrict__ out) {
    __shared__ short Kt[4096];    // [64 key][64 d], 16B-unit col ^ (row&7)
    __shared__ short KKt[4096];
    __shared__ short VTt[4096];   // [64 d][64 key], same swizzle
    __shared__ short Plds[4][16][72];  // per-wave P: [q][key], padded rows
    int dd = blockIdx.x;
    int xcd = dd & 7, rr = dd >> 3;
    int r0 = (rr & 15) * 64;
    int bh = (rr >> 4) * 8 + xcd;
    int t = threadIdx.x, w = t >> 6, l = t & 63, lr = l & 15, lg = l >> 4;
    const short* qp = Qb + (size_t)bh * 65536;
    const short* kp = Kb + (size_t)bh * 65536;
    const short* kk = KK + (size_t)bh * 65536;
    const short* vt = VT + (size_t)bh * 65536;

    // Q B-operand frags for this wave's 16 q-rows (K=128 augmented).
    // bfr[2..3] = -(1/6)*(Q[n-1]+Q[n]+Q[n+1]) per-lane from global (zero-padded).
    int nq = r0 + w * 16 + lr;
    const short* qrow = qp + (size_t)nq * 64 + lg * 8;
    short8 bfr[4];
    bfr[0] = *(const short8*)(qrow);
    bfr[1] = *(const short8*)(qrow + 32);
    {
        float s0[8], s1[8];
#pragma unroll
        for (int e = 0; e < 8; ++e) { s0[e] = b2f(bfr[0][e]); s1[e] = b2f(bfr[1][e]); }
        if (nq > 0) {
            short8 m0 = *(const short8*)(qrow - 64);
            short8 m1 = *(const short8*)(qrow - 64 + 32);
#pragma unroll
            for (int e = 0; e < 8; ++e) { s0[e] += b2f(m0[e]); s1[e] += b2f(m1[e]); }
        }
        if (nq < 1023) {
            short8 p0 = *(const short8*)(qrow + 64);
            short8 p1 = *(const short8*)(qrow + 64 + 32);
#pragma unroll
            for (int e = 0; e < 8; ++e) { s0[e] += b2f(p0[e]); s1[e] += b2f(p1[e]); }
        }
#pragma unroll
        for (int e = 0; e < 8; ++e) {
            bfr[2][e] = f2b(-(1.0f / 6.0f) * s0[e]);
            bfr[3][e] = f2b(-(1.0f / 6.0f) * s1[e]);
        }
    }

    // Staging: unit u covers rows (u>>3), 16B col (u&7); source pre-swizzled.
    int srow = t >> 3, sc = ((t & 7) ^ (srow & 7)) * 8;
    const short* gk = kp + srow * 64 + sc;       // +2048 shorts for second half
    const short* gkk = kk + srow * 64 + sc;
    const short* gv = vt + srow * 1024 + sc;     // +32768 for second half
    short* dk0 = Kt + w * 512;   short* dk1 = Kt + 2048 + w * 512;
    short* dkk0 = KKt + w * 512; short* dkk1 = KKt + 2048 + w * 512;
    short* dv0 = VTt + w * 512;  short* dv1 = VTt + 2048 + w * 512;
    short* pw = &Plds[w][0][0];
    short* pwr = pw + lr * 72;

    f32x4 O[4];
#pragma unroll
    for (int m = 0; m < 4; ++m) O[m] = (f32x4){0.f, 0.f, 0.f, 0.f};
    float m_run = -1e30f, l_run = 0.f;

    for (int tt = 0; tt < 16; ++tt) {
        int ko = tt * 64;  // key offset
        gload_lds16(gk + ko * 64, dk0);
        gload_lds16(gk + ko * 64 + 2048, dk1);
        gload_lds16(gkk + ko * 64, dkk0);
        gload_lds16(gkk + ko * 64 + 2048, dkk1);
        gload_lds16(gv + ko, dv0);
        gload_lds16(gv + ko + 32768, dv1);
        __syncthreads();  // drains vmcnt: staging complete

        // QK^T: D[key][q] (log2-space scores), 64 keys x 16 q per wave.
        f32x4 sacc[4];
        __builtin_amdgcn_s_setprio(1);
#pragma unroll
        for (int ct = 0; ct < 4; ++ct) {
            int r = ct * 16 + lr, rs = r * 64, rx = r & 7;
            short8 a0 = *(short8*)&Kt[rs + (((0 + lg) ^ rx) << 3)];
            short8 a1 = *(short8*)&Kt[rs + (((4 + lg) ^ rx) << 3)];
            short8 a2 = *(short8*)&KKt[rs + (((0 + lg) ^ rx) << 3)];
            short8 a3 = *(short8*)&KKt[rs + (((4 + lg) ^ rx) << 3)];
            f32x4 s_ = (f32x4){0.f, 0.f, 0.f, 0.f};
            s_ = MFMA16(a0, bfr[0], s_);
            s_ = MFMA16(a1, bfr[1], s_);
            s_ = MFMA16(a2, bfr[2], s_);
            s_ = MFMA16(a3, bfr[3], s_);
            sacc[ct] = s_;
        }
        __builtin_amdgcn_s_setprio(0);
        // Online softmax in log2 space (q = lr lane-local; keys split across lg).
        float mt_ = fmaxf(fmaxf(fmaxf(sacc[0][0], sacc[0][1]), fmaxf(sacc[0][2], sacc[0][3])),
                          fmaxf(fmaxf(sacc[1][0], sacc[1][1]), fmaxf(sacc[1][2], sacc[1][3])));
        float mt2 = fmaxf(fmaxf(fmaxf(sacc[2][0], sacc[2][1]), fmaxf(sacc[2][2], sacc[2][3])),
                          fmaxf(fmaxf(sacc[3][0], sacc[3][1]), fmaxf(sacc[3][2], sacc[3][3])));
        mt_ = fmaxf(mt_, mt2);
        mt_ = fmaxf(mt_, __shfl_xor(mt_, 16));
        mt_ = fmaxf(mt_, __shfl_xor(mt_, 32));
        // Defer-max: only rescale when the tile max pushes past m_run + 8.
        if (__any(mt_ > m_run + 8.0f)) {
            float mnew = fmaxf(m_run, mt_);
            float sc_ = __builtin_amdgcn_exp2f(m_run - mnew);
            m_run = mnew;
            l_run *= sc_;
#pragma unroll
            for (int m = 0; m < 4; ++m)
#pragma unroll
                for (int i = 0; i < 4; ++i) O[m][i] *= sc_;
        }
        float ps = 0.f;
#pragma unroll
        for (int ct = 0; ct < 4; ++ct) {
            float p0 = __builtin_amdgcn_exp2f(sacc[ct][0] - m_run);
            float p1 = __builtin_amdgcn_exp2f(sacc[ct][1] - m_run);
            float p2 = __builtin_amdgcn_exp2f(sacc[ct][2] - m_run);
            float p3 = __builtin_amdgcn_exp2f(sacc[ct][3] - m_run);
            ps += (p0 + p1) + (p2 + p3);
            uint2 wv;
            wv.x = pk2(p0, p1);
            wv.y = pk2(p2, p3);
            *(uint2*)&pwr[ct * 16 + lg * 4] = wv;
        }
        l_run += ps;
        // PV: O^T[d][q] += VT-tile . P-tile
        short8 pb0 = *(short8*)&pwr[lg * 8];
        short8 pb1 = *(short8*)&pwr[32 + lg * 8];
        __builtin_amdgcn_s_setprio(1);
#pragma unroll
        for (int m = 0; m < 4; ++m) {
            int r = m * 16 + lr, rs = r * 64, rx = r & 7;
            short8 v0 = *(short8*)&VTt[rs + (((0 + lg) ^ rx) << 3)];
            short8 v1 = *(short8*)&VTt[rs + (((4 + lg) ^ rx) << 3)];
            O[m] = MFMA16(v0, pb0, O[m]);
            O[m] = MFMA16(v1, pb1, O[m]);
        }
        __builtin_amdgcn_s_setprio(0);
        __syncthreads();  // all waves done reading tile before next stage
    }

    l_run += __shfl_xor(l_run, 16);
    l_run += __shfl_xor(l_run, 32);
    float inv = 1.f / l_run;
    int b = bh / 12, h = bh - b * 12;
    int q = r0 + w * 16 + lr;
    float* ob = out + (size_t)(b * 1024 + q) * 768 + h * 64;
#pragma unroll
    for (int m = 0; m < 4; ++m) {
        float4 o4;
        o4.x = O[m][0] * inv; o4.y = O[m][1] * inv;
        o4.z = O[m][2] * inv; o4.w = O[m][3] * inv;
        *(float4*)(ob + m * 16 + lg * 4) = o4;
    }
}

extern "C" void kernel_launch(void* const* d_in, const int* in_sizes, int n_in,
                              void* d_out, int out_size, void* d_ws, size_t ws_size,
                              hipStream_t stream) {
    const float* x  = (const float*)d_in[0];
    const float* W  = (const float*)d_in[1];
    const float* qb = (const float*)d_in[2];
    const float* lg = (const float*)d_in[3];
    const float* lb = (const float*)d_in[4];
    float* out = (float*)d_out;
    char* ws = (char*)d_ws;
    // Workspace layout (peak 28,704,768 bytes):
    short* xnb = (short*)(ws + 0);         // [4096][768] bf16 (dead after gemm)
    short* Wb  = (short*)(ws + 6291456);   // [2304][768] bf16
    short* Qb  = (short*)(ws + 9830400);   // [48][1024][64] bf16, pre-scaled by cq*log2e
    short* Kb  = (short*)(ws + 16121856);  // [48][1024][64] bf16
    short* VT  = (short*)(ws + 22413312);  // [48][64][1024] bf16
    short* KK  = (short*)(ws + 0);         // [48][1024][64] bf16, overlays dead xnb

    hipLaunchKernelGGL(prep_kernel, dim3(2752), dim3(256), 0, stream, x, lg, lb, W, xnb, Wb);
    hipLaunchKernelGGL(qkv_gemm, dim3(64, 18), dim3(256), 0, stream, xnb, Wb, qb, Qb, Kb, VT);
    hipLaunchKernelGGL(kk_kernel, dim3(32, 48), dim3(256), 0, stream, Kb, KK);
    hipLaunchKernelGGL(attn_kernel, dim3(768), dim3(256), 0, stream, Qb, Kb, KK, VT, out);
}